// Round 6
// baseline (213.885 us; speedup 1.0000x reference)
//
#include <hip/hip_runtime.h>
#include <hip/hip_fp16.h>

// Fused WeightedMAE + Patch-SSIM loss for (8,8,512,512) fp32 inputs.
// One block per (patch, channel): 4096 blocks x 512 threads.
// DESIGNED FOR 64 VGPRs (the compiler refuses to allocate more; R2-R5
// evidence): vertical-first separable conv, column-per-thread.
// Phase A: load 64x64 tile, stage x=in+out, y=tgt fp16 in LDS; fused MAE.
// Phase V: vertical 11-tap conv of {x,y,xx,yy,xy} (xx/yy/xy on the fly),
//          thread owns (col, 3 out rows): 15 named accumulators, reads at
//          lane=col stride-2B -> conflict-free. Writes 5 fp16 V fields.
// Phase H: horizontal 11-tap conv on V, thread owns (row, 3 out cols):
//          13-tap window, 15 named accumulators + SSIM formula.
// Reduction: wave shuffle -> LDS -> atomicAdd; tiny finalize kernel.
// LDS = 2*64*68*2 + 5*54*66*2 + 96 = 52.0 KB -> 3 blocks/CU (24 waves).

#define C1c 1.0e-4f
#define C2c 9.0e-4f

struct alignas(8) h4 { __half2 a, b; };

__global__ __launch_bounds__(512)
void fused_loss_kernel(const float* __restrict__ in,
                       const float* __restrict__ outp,
                       const float* __restrict__ tgt,
                       float* __restrict__ ws) {
    __shared__ __half xt[64][68];     // stride 136 B (8B-aligned h4 writes)
    __shared__ __half yt[64][68];
    __shared__ __half V0[54][66];     // vertical mu1 field
    __shared__ __half V1[54][66];     // mu2
    __shared__ __half V2[54][66];     // xx
    __shared__ __half V3[54][66];     // yy
    __shared__ __half V4[54][66];     // xy
    __shared__ float  red[8][3];

    const int tid = threadIdx.x;
    const int pc  = blockIdx.x;           // 0..4095
    const int ch  = pc & 7;
    const int p   = pc >> 3;              // 0..511
    const int b   = p >> 6;
    const int ph  = (p >> 3) & 7;
    const int pw  = p & 7;

    // gaussian weights (float32 pipeline, matches np)
    float wgt[11];
    {
        float s = 0.0f;
#pragma unroll
        for (int j = 0; j < 11; ++j) {
            float d = (float)(j - 5);
            wgt[j] = expf(-d * d / 4.5f);
            s += wgt[j];
        }
        float invs = 1.0f / s;
#pragma unroll
        for (int j = 0; j < 11; ++j) wgt[j] *= invs;
    }

    // ---------------- Phase A: load tile, stage fp16, fused MAE ----------
    float mae_num = 0.0f, mae_den = 0.0f;
    const size_t img_base =
        ((size_t)(b * 8 + ch) * 512 + (size_t)(ph * 64)) * 512 + (size_t)(pw * 64);

#pragma unroll
    for (int i = 0; i < 2; ++i) {
        const int pos = tid + i * 512;        // 0..1023 float4 slots
        const int r   = pos >> 4;             // 0..63
        const int c4  = (pos & 15) << 2;      // 0..60
        const size_t off = img_base + (size_t)r * 512 + (size_t)c4;
        const float4 iv = *(const float4*)(in   + off);
        const float4 ov = *(const float4*)(outp + off);
        const float4 tv = *(const float4*)(tgt  + off);
        const float x0 = iv.x + ov.x, x1 = iv.y + ov.y;
        const float x2 = iv.z + ov.z, x3 = iv.w + ov.w;
        h4 xv; xv.a = __floats2half2_rn(x0, x1); xv.b = __floats2half2_rn(x2, x3);
        h4 yv; yv.a = __floats2half2_rn(tv.x, tv.y); yv.b = __floats2half2_rn(tv.z, tv.w);
        *(h4*)&xt[r][c4] = xv;
        *(h4*)&yt[r][c4] = yv;
        {   // MAE: hp = tgt - in; w = |hp|>0; num += w*|out - hp| (branchless)
            float hp, w;
            hp = tv.x - iv.x; w = (fabsf(hp) > 0.0f) ? 1.0f : 0.0f;
            mae_den += w; mae_num = fmaf(w, fabsf(ov.x - hp), mae_num);
            hp = tv.y - iv.y; w = (fabsf(hp) > 0.0f) ? 1.0f : 0.0f;
            mae_den += w; mae_num = fmaf(w, fabsf(ov.y - hp), mae_num);
            hp = tv.z - iv.z; w = (fabsf(hp) > 0.0f) ? 1.0f : 0.0f;
            mae_den += w; mae_num = fmaf(w, fabsf(ov.z - hp), mae_num);
            hp = tv.w - iv.w; w = (fabsf(hp) > 0.0f) ? 1.0f : 0.0f;
            mae_den += w; mae_num = fmaf(w, fabsf(ov.w - hp), mae_num);
        }
    }
    __syncthreads();

    // ---------------- Phase V: vertical conv, column-per-thread ----------
    // 18 row-blocks (3 out rows) x 64 cols = 1152 units over 512 threads.
#pragma unroll
    for (int it = 0; it < 3; ++it) {
        const int u = tid + it * 512;
        if (u < 1152) {
            const int c  = u & 63;
            const int rb = (u >> 6) * 3;      // 0,3,..,51
            float a0[3] = {0,0,0}, a1[3] = {0,0,0}, a2[3] = {0,0,0};
            float a3[3] = {0,0,0}, a4[3] = {0,0,0};
#pragma unroll
            for (int ir = 0; ir < 13; ++ir) {
                const float x = __half2float(xt[rb + ir][c]);
                const float y = __half2float(yt[rb + ir][c]);
                const float xx = x * x, yy = y * y, xy = x * y;
#pragma unroll
                for (int i = 0; i < 3; ++i) {
                    const int j = ir - i;
                    if (j >= 0 && j <= 10) {          // folds at compile time
                        const float w = wgt[j];
                        a0[i] = fmaf(w, x,  a0[i]);
                        a1[i] = fmaf(w, y,  a1[i]);
                        a2[i] = fmaf(w, xx, a2[i]);
                        a3[i] = fmaf(w, yy, a3[i]);
                        a4[i] = fmaf(w, xy, a4[i]);
                    }
                }
            }
#pragma unroll
            for (int i = 0; i < 3; ++i) {
                V0[rb + i][c] = __float2half_rn(a0[i]);
                V1[rb + i][c] = __float2half_rn(a1[i]);
                V2[rb + i][c] = __float2half_rn(a2[i]);
                V3[rb + i][c] = __float2half_rn(a3[i]);
                V4[rb + i][c] = __float2half_rn(a4[i]);
            }
        }
    }
    __syncthreads();

    // ---------------- Phase H: horizontal conv + SSIM --------------------
    // 54 rows x 18 col-blocks (3 out cols) = 972 units over 512 threads.
    float ssim_acc = 0.0f;
#pragma unroll
    for (int it = 0; it < 2; ++it) {
        const int v = tid + it * 512;
        if (v < 972) {
            const int r  = v / 18;
            const int cb = v - r * 18;
            const int c0 = cb * 3;            // 0..51
            float m1[3] = {0,0,0}, m2[3] = {0,0,0}, s2[3] = {0,0,0};
            float s3[3] = {0,0,0}, s4[3] = {0,0,0};
#pragma unroll
            for (int t = 0; t < 13; ++t) {
                const float f0 = __half2float(V0[r][c0 + t]);
                const float f1 = __half2float(V1[r][c0 + t]);
                const float f2 = __half2float(V2[r][c0 + t]);
                const float f3 = __half2float(V3[r][c0 + t]);
                const float f4 = __half2float(V4[r][c0 + t]);
#pragma unroll
                for (int k = 0; k < 3; ++k) {
                    const int j = t - k;
                    if (j >= 0 && j <= 10) {          // folds at compile time
                        const float w = wgt[j];
                        m1[k] = fmaf(w, f0, m1[k]);
                        m2[k] = fmaf(w, f1, m2[k]);
                        s2[k] = fmaf(w, f2, s2[k]);
                        s3[k] = fmaf(w, f3, s3[k]);
                        s4[k] = fmaf(w, f4, s4[k]);
                    }
                }
            }
#pragma unroll
            for (int k = 0; k < 3; ++k) {
                const float mu1 = m1[k], mu2 = m2[k];
                const float mu1sq = mu1 * mu1;
                const float mu2sq = mu2 * mu2;
                const float mu12  = mu1 * mu2;
                const float num = (2.0f * mu12 + C1c) * (2.0f * (s4[k] - mu12) + C2c);
                const float den = (mu1sq + mu2sq + C1c) *
                                  ((s2[k] - mu1sq) + (s3[k] - mu2sq) + C2c);
                ssim_acc += num / den;
            }
        }
    }

    // ---------------- Reduction ----------------
    float v0 = mae_num, v1 = mae_den, v2 = ssim_acc;
#pragma unroll
    for (int off = 32; off >= 1; off >>= 1) {
        v0 += __shfl_down(v0, off);
        v1 += __shfl_down(v1, off);
        v2 += __shfl_down(v2, off);
    }
    const int wave = tid >> 6;
    const int lane = tid & 63;
    if (lane == 0) { red[wave][0] = v0; red[wave][1] = v1; red[wave][2] = v2; }
    __syncthreads();
    if (tid == 0) {
        float r0 = 0.f, r1 = 0.f, r2 = 0.f;
#pragma unroll
        for (int w = 0; w < 8; ++w) { r0 += red[w][0]; r1 += red[w][1]; r2 += red[w][2]; }
        atomicAdd(&ws[0], r0);
        atomicAdd(&ws[1], r1);
        atomicAdd(&ws[2], r2);
    }
}

__global__ void finalize_kernel(const float* __restrict__ ws, float* __restrict__ out) {
    if (threadIdx.x == 0 && blockIdx.x == 0) {
        const float mae = ws[0] / (ws[1] + 1e-8f);
        const float ssim_mean = ws[2] * (1.0f / 11943936.0f); // 4096 * 54 * 54
        out[0] = 0.5f * mae + 0.5f * (1.0f - ssim_mean);
    }
}

extern "C" void kernel_launch(void* const* d_in, const int* in_sizes, int n_in,
                              void* d_out, int out_size, void* d_ws, size_t ws_size,
                              hipStream_t stream) {
    const float* in   = (const float*)d_in[0];
    const float* outp = (const float*)d_in[1];
    const float* tgt  = (const float*)d_in[2];
    float* ws = (float*)d_ws;

    hipMemsetAsync(d_ws, 0, 3 * sizeof(float), stream);
    fused_loss_kernel<<<4096, 512, 0, stream>>>(in, outp, tgt, ws);
    finalize_kernel<<<1, 64, 0, stream>>>(ws, (float*)d_out);
}

// Round 7
// 183.906 us; speedup vs baseline: 1.1630x; 1.1630x over previous
//
#include <hip/hip_runtime.h>
#include <hip/hip_fp16.h>

// Fused WeightedMAE + Patch-SSIM loss for (8,8,512,512) fp32 inputs.
// One block per (patch, channel): 4096 blocks x 512 threads.
// Vertical-first separable conv, designed for the 64-VGPR budget the
// compiler insists on (R2-R6), with WIDE LDS accesses (R6 lesson: 208
// scalar ds_read_u16/thread = ~64 us of LDS pipe; now ~97 wide ops).
// Phase A: load 64x64 tile, stage (x=in+out, y=tgt) packed __half2; MAE.
// Phase V: vertical 11-tap conv of {x,y,xx,yy,xy}; thread owns (col, 3
//          out rows); reads 13 x b32 (packed xy); 15 named accumulators.
// Phase H: horizontal 11-tap conv; thread owns (row, 4 out cols);
//          field-at-a-time b64 window reads (4 per field), 20 accs.
// Gaussian weights are compile-time constants (no expf, frees VGPRs).
// LDS = 64*64*4 + 5*54*68*2 + 96 = 53.2 KB -> 3 blocks/CU.

#define C1c 1.0e-4f
#define C2c 9.0e-4f

struct alignas(8)  h4  { __half2 a, b; };
struct alignas(16) xy4 { __half2 v[4]; };

// exp(-(j-5)^2/4.5)/sum, float32 pipeline (matches np to ~1e-7)
#define W0 0.00102838f
#define W1 0.00759874f
#define W2 0.03600076f
#define W3 0.10936068f
#define W4 0.21300564f
#define W5 0.26601172f
__device__ __constant__ float WGT[11] = {W0, W1, W2, W3, W4, W5, W4, W3, W2, W1, W0};

__global__ __launch_bounds__(512)
void fused_loss_kernel(const float* __restrict__ in,
                       const float* __restrict__ outp,
                       const float* __restrict__ tgt,
                       float* __restrict__ ws) {
    __shared__ alignas(16) __half2 xyt[64][64];   // (x,y) packed per pixel
    __shared__ alignas(16) __half V0[54][68];     // vertical conv fields
    __shared__ alignas(16) __half V1[54][68];
    __shared__ alignas(16) __half V2[54][68];
    __shared__ alignas(16) __half V3[54][68];
    __shared__ alignas(16) __half V4[54][68];
    __shared__ float red[8][3];

    const int tid = threadIdx.x;
    const int pc  = blockIdx.x;           // 0..4095
    const int ch  = pc & 7;
    const int p   = pc >> 3;              // 0..511
    const int b   = p >> 6;
    const int ph  = (p >> 3) & 7;
    const int pw  = p & 7;

    // ---------------- Phase A: load tile, stage packed fp16, MAE ---------
    float mae_num = 0.0f, mae_den = 0.0f;
    const size_t img_base =
        ((size_t)(b * 8 + ch) * 512 + (size_t)(ph * 64)) * 512 + (size_t)(pw * 64);

#pragma unroll
    for (int i = 0; i < 2; ++i) {
        const int pos = tid + i * 512;        // 0..1023 float4 slots
        const int r   = pos >> 4;             // 0..63
        const int c4  = (pos & 15) << 2;      // 0..60
        const size_t off = img_base + (size_t)r * 512 + (size_t)c4;
        const float4 iv = *(const float4*)(in   + off);
        const float4 ov = *(const float4*)(outp + off);
        const float4 tv = *(const float4*)(tgt  + off);
        const float x0 = iv.x + ov.x, x1 = iv.y + ov.y;
        const float x2 = iv.z + ov.z, x3 = iv.w + ov.w;
        xy4 q;
        q.v[0] = __floats2half2_rn(x0, tv.x);
        q.v[1] = __floats2half2_rn(x1, tv.y);
        q.v[2] = __floats2half2_rn(x2, tv.z);
        q.v[3] = __floats2half2_rn(x3, tv.w);
        *(xy4*)&xyt[r][c4] = q;
        {   // MAE: hp = tgt - in; w = |hp|>0; num += w*|out - hp| (branchless)
            float hp, w;
            hp = tv.x - iv.x; w = (fabsf(hp) > 0.0f) ? 1.0f : 0.0f;
            mae_den += w; mae_num = fmaf(w, fabsf(ov.x - hp), mae_num);
            hp = tv.y - iv.y; w = (fabsf(hp) > 0.0f) ? 1.0f : 0.0f;
            mae_den += w; mae_num = fmaf(w, fabsf(ov.y - hp), mae_num);
            hp = tv.z - iv.z; w = (fabsf(hp) > 0.0f) ? 1.0f : 0.0f;
            mae_den += w; mae_num = fmaf(w, fabsf(ov.z - hp), mae_num);
            hp = tv.w - iv.w; w = (fabsf(hp) > 0.0f) ? 1.0f : 0.0f;
            mae_den += w; mae_num = fmaf(w, fabsf(ov.w - hp), mae_num);
        }
    }
    __syncthreads();

    // ---------------- Phase V: vertical conv, column-per-thread ----------
    // 18 row-blocks (3 out rows) x 64 cols = 1152 units over 512 threads.
#pragma unroll
    for (int it = 0; it < 3; ++it) {
        const int u = tid + it * 512;
        if (u < 1152) {
            const int c  = u & 63;
            const int rb = (u >> 6) * 3;      // 0,3,..,51
            float a0[3] = {0,0,0}, a1[3] = {0,0,0}, a2[3] = {0,0,0};
            float a3[3] = {0,0,0}, a4[3] = {0,0,0};
#pragma unroll
            for (int ir = 0; ir < 13; ++ir) {
                const __half2 q = xyt[rb + ir][c];
                const float x = __low2float(q);
                const float y = __high2float(q);
                const float xx = x * x, yy = y * y, xy = x * y;
#pragma unroll
                for (int i = 0; i < 3; ++i) {
                    const int j = ir - i;
                    if (j >= 0 && j <= 10) {          // folds at compile time
                        const float w = WGT[j];
                        a0[i] = fmaf(w, x,  a0[i]);
                        a1[i] = fmaf(w, y,  a1[i]);
                        a2[i] = fmaf(w, xx, a2[i]);
                        a3[i] = fmaf(w, yy, a3[i]);
                        a4[i] = fmaf(w, xy, a4[i]);
                    }
                }
            }
#pragma unroll
            for (int i = 0; i < 3; ++i) {
                V0[rb + i][c] = __float2half_rn(a0[i]);
                V1[rb + i][c] = __float2half_rn(a1[i]);
                V2[rb + i][c] = __float2half_rn(a2[i]);
                V3[rb + i][c] = __float2half_rn(a3[i]);
                V4[rb + i][c] = __float2half_rn(a4[i]);
            }
        }
    }
    __syncthreads();

    // ---------------- Phase H: horizontal conv + SSIM --------------------
    // 54 rows x 14 col-blocks (4 out cols) = 756 units over 512 threads.
    // Field-at-a-time: 4 x b64 window reads, 16 cvt, 44 fma per field.
#define HFIELD(VARR, FI)                                                     \
    {                                                                        \
        const h4 p0 = *(const h4*)&VARR[r][c0];                              \
        const h4 p1 = *(const h4*)&VARR[r][c0 + 4];                          \
        const h4 p2 = *(const h4*)&VARR[r][c0 + 8];                          \
        const h4 p3 = *(const h4*)&VARR[r][c0 + 12];                         \
        float win[16];                                                       \
        win[ 0] = __low2float(p0.a); win[ 1] = __high2float(p0.a);           \
        win[ 2] = __low2float(p0.b); win[ 3] = __high2float(p0.b);           \
        win[ 4] = __low2float(p1.a); win[ 5] = __high2float(p1.a);           \
        win[ 6] = __low2float(p1.b); win[ 7] = __high2float(p1.b);           \
        win[ 8] = __low2float(p2.a); win[ 9] = __high2float(p2.a);           \
        win[10] = __low2float(p2.b); win[11] = __high2float(p2.b);           \
        win[12] = __low2float(p3.a); win[13] = __high2float(p3.a);           \
        win[14] = __low2float(p3.b); win[15] = __high2float(p3.b);           \
        _Pragma("unroll")                                                    \
        for (int k = 0; k < 4; ++k) {                                        \
            float s = 0.0f;                                                  \
            _Pragma("unroll")                                                \
            for (int j = 0; j < 11; ++j) s = fmaf(WGT[j], win[k + j], s);    \
            acc[FI][k] = s;                                                  \
        }                                                                    \
    }

    float ssim_acc = 0.0f;
#pragma unroll
    for (int it = 0; it < 2; ++it) {
        const int v = tid + it * 512;
        if (v < 756) {
            const int r  = v / 14;
            const int cu = v - r * 14;
            const int c0 = cu << 2;           // 0..52
            float acc[5][4];
            HFIELD(V0, 0)
            HFIELD(V1, 1)
            HFIELD(V2, 2)
            HFIELD(V3, 3)
            HFIELD(V4, 4)
#pragma unroll
            for (int k = 0; k < 4; ++k) {
                if (c0 + k < 54) {
                    const float mu1 = acc[0][k], mu2 = acc[1][k];
                    const float sxx = acc[2][k], syy = acc[3][k], sxy = acc[4][k];
                    const float mu1sq = mu1 * mu1;
                    const float mu2sq = mu2 * mu2;
                    const float mu12  = mu1 * mu2;
                    const float num = (2.0f * mu12 + C1c) * (2.0f * (sxy - mu12) + C2c);
                    const float den = (mu1sq + mu2sq + C1c) *
                                      ((sxx - mu1sq) + (syy - mu2sq) + C2c);
                    ssim_acc += num / den;
                }
            }
        }
    }

    // ---------------- Reduction ----------------
    float v0 = mae_num, v1 = mae_den, v2 = ssim_acc;
#pragma unroll
    for (int off = 32; off >= 1; off >>= 1) {
        v0 += __shfl_down(v0, off);
        v1 += __shfl_down(v1, off);
        v2 += __shfl_down(v2, off);
    }
    const int wave = tid >> 6;
    const int lane = tid & 63;
    if (lane == 0) { red[wave][0] = v0; red[wave][1] = v1; red[wave][2] = v2; }
    __syncthreads();
    if (tid == 0) {
        float r0 = 0.f, r1 = 0.f, r2 = 0.f;
#pragma unroll
        for (int w = 0; w < 8; ++w) { r0 += red[w][0]; r1 += red[w][1]; r2 += red[w][2]; }
        atomicAdd(&ws[0], r0);
        atomicAdd(&ws[1], r1);
        atomicAdd(&ws[2], r2);
    }
}

__global__ void finalize_kernel(const float* __restrict__ ws, float* __restrict__ out) {
    if (threadIdx.x == 0 && blockIdx.x == 0) {
        const float mae = ws[0] / (ws[1] + 1e-8f);
        const float ssim_mean = ws[2] * (1.0f / 11943936.0f); // 4096 * 54 * 54
        out[0] = 0.5f * mae + 0.5f * (1.0f - ssim_mean);
    }
}

extern "C" void kernel_launch(void* const* d_in, const int* in_sizes, int n_in,
                              void* d_out, int out_size, void* d_ws, size_t ws_size,
                              hipStream_t stream) {
    const float* in   = (const float*)d_in[0];
    const float* outp = (const float*)d_in[1];
    const float* tgt  = (const float*)d_in[2];
    float* ws = (float*)d_ws;

    hipMemsetAsync(d_ws, 0, 3 * sizeof(float), stream);
    fused_loss_kernel<<<4096, 512, 0, stream>>>(in, outp, tgt, ws);
    finalize_kernel<<<1, 64, 0, stream>>>(ws, (float*)d_out);
}